// Round 1
// 497.010 us; speedup vs baseline: 1.1497x; 1.1497x over previous
//
#include <hip/hip_runtime.h>

// N=1024, D=16, H=32, 3H=96.  All tensors fp32 (per reference dtypes).

typedef _Float16 hv2 __attribute__((ext_vector_type(2)));
typedef _Float16 hv8 __attribute__((ext_vector_type(8)));
typedef float    fv4 __attribute__((ext_vector_type(4)));
typedef unsigned uv4 __attribute__((ext_vector_type(4)));

// pack two fp32 -> f16 pair bits (v_cvt_pkrtz_f16_f32) -- weights only (RTZ)
__device__ __forceinline__ unsigned pkh(float a, float b) {
    auto t = __builtin_amdgcn_cvt_pkrtz(a, b);
    return __builtin_bit_cast(unsigned, t);
}
__device__ __forceinline__ fv4 splat4(float v) { return fv4{v, v, v, v}; }
// fast reciprocal: v_rcp_f32 (~1 ulp; verified accuracy-neutral in prior session)
#if __has_builtin(__builtin_amdgcn_rcpf)
__device__ __forceinline__ float frcp(float x) { return __builtin_amdgcn_rcpf(x); }
#else
__device__ __forceinline__ float frcp(float x) { return 1.f / x; }
#endif
// dot2: c += a.x*b.x + a.y*b.y   (f16 inputs, f32 accumulate)
#if __has_builtin(__builtin_amdgcn_fdot2)
__device__ __forceinline__ float d2(unsigned a, unsigned b, float c) {
    return __builtin_amdgcn_fdot2(__builtin_bit_cast(hv2, a),
                                  __builtin_bit_cast(hv2, b), c, false);
}
#else
__device__ __forceinline__ float d2(unsigned a, unsigned b, float c) {
    hv2 x = __builtin_bit_cast(hv2, a), y = __builtin_bit_cast(hv2, b);
    return fmaf((float)x.x, (float)y.x, fmaf((float)x.y, (float)y.y, c));
}
#endif
// lane 2k reads lane 2k+1 (quad_perm [1,0,3,2] = 0xB1); all lanes active
__device__ __forceinline__ float dpp_xor1(float x) {
    int r = __builtin_amdgcn_update_dpp(0, __builtin_bit_cast(int, x),
                                        0xB1, 0xF, 0xF, true);
    return __builtin_bit_cast(float, r);
}
// v_permlane32_swap_b32 d, s  (d=s=x):
//   d := x's lanes 0..31 replicated to both halves (lo-half value for m=l&31)
//   s := x's lanes 32..63 replicated to both halves (hi-half value)
__device__ __forceinline__ void half_swap(float x, float& lo_all, float& hi_all) {
    float d = x, s = x;
    asm("v_permlane32_swap_b32 %0, %1" : "+v"(d), "+v"(s));
    lo_all = d;
    hi_all = s;
}

// ---------------------------------------------------------------------------
// K1/K3: pairwise rank-split (unchanged, proven).
// ---------------------------------------------------------------------------
__global__ void proj1_kernel(const float* __restrict__ x, const float* __restrict__ w,
                             const float* __restrict__ bias,
                             float* __restrict__ A, float* __restrict__ B) {
    int idx = blockIdx.x * 256 + threadIdx.x;      // 0..32767
    int i = idx >> 5, h = idx & 31;
    float sa = bias[h];
    float sb = 0.f;
#pragma unroll
    for (int d = 0; d < 16; ++d) {
        float xv = x[i * 16 + d];
        float wa = w[h * 32 + d];
        float wb = w[h * 32 + 16 + d];
        sa += (wa - wb) * xv;
        sb += wb * xv;
    }
    A[i * 32 + h] = sa;
    B[i * 32 + h] = sb;
}

__global__ void proj2_kernel(const float* __restrict__ h1, const float* __restrict__ w,
                             const float* __restrict__ bias,
                             float* __restrict__ A, float* __restrict__ B) {
    int idx = blockIdx.x * 256 + threadIdx.x;      // 0..32767
    int i = idx >> 5, h = idx & 31;
    float sa = bias[h];
    float sb = 0.f;
#pragma unroll
    for (int k = 0; k < 32; ++k) {
        float hv = h1[i * 32 + k];
        float wa = w[h * 64 + k];
        float wb = w[h * 64 + 32 + k];
        sa += (wa - wb) * hv;
        sb += wb * hv;
    }
    A[i * 32 + h] = sa;
    B[i * 32 + h] = sb;
}

// ---------------------------------------------------------------------------
// GRU, one chain per wave, 1024 blocks (1 wave on every SIMD).
//   CHUNK phase (per 16 steps, off the serial path): unchanged -- XG via 6
//   MFMAs -> LDS; r/z tiles store exp(-XG), n tiles raw XG.
//   SERIAL phase (per step), restructured this round:
//     * h broadcast WITHOUT LDS: pack (h[2k],h[2k+1]) as f16 pairs in even
//       lanes (DPP xor-1 + RNE cvts, same rounding as the old ds_write_b16
//       path), then 16x v_readlane -> wave-uniform scalars feeding v_dot2 as
//       the one legal scalar operand.  Removes the ~120cy ds_read round-trip
//       that sat on the recurrence's critical path.
//     * r/z half-split: lanes<32 accumulate r-rows, lanes>=32 z-rows (per-lane
//       weights, shared instructions); ONE v_permlane32_swap_b32 gives every
//       lane both hr and hz.  Removes 16 of 48 dot2s per step.  n stays fully
//       mirrored (its k-split would need per-half scalar operands).
//     * summation trees / gate math bit-identical to the previous kernel.
// ---------------------------------------------------------------------------
__global__ __launch_bounds__(64, 1) void gru_kernel(
    const float* __restrict__ A, const float* __restrict__ B,
    const float* __restrict__ wih, const float* __restrict__ whh,
    const float* __restrict__ bih, const float* __restrict__ bhh,
    float* __restrict__ h_out) {
    const int l = threadIdx.x;         // 0..63
    const int q = l >> 4;              // k-slot group (chunk MFMA)
    const int m0 = l & 15;             // MFMA col
    const int m = l & 31;              // gate/hidden index (halves mirrored)
    const int c = blockIdx.x;          // chain

    __shared__ float xg[6][16][17];    // [tile][t_local][col] (+pad)

    // ---- chunk-phase weights: Wih B-frags (k-slot (k,k+16) pairs) ----
    hv8 WI[6];
#pragma unroll
    for (int T = 0; T < 6; ++T) {
        int g = 16 * T + m0;
        uv4 wi;
#pragma unroll
        for (int r = 0; r < 4; ++r) {
            int lo = 4 * q + r;
            wi[r] = pkh(wih[g * 32 + lo], wih[g * 32 + lo + 16]);
        }
        WI[T] = __builtin_bit_cast(hv8, wi);
    }
    float bi[6];
#pragma unroll
    for (int T = 0; T < 6; ++T) bi[T] = bih[16 * T + m0];

    // ---- serial-phase weights ----
    // lanes<32: whh r-rows (m);  lanes>=32: whh z-rows (32+m).  n-rows mirrored.
    const int grow = (l < 32) ? m : (32 + m);
    unsigned grz[16], wn2[16];
#pragma unroll
    for (int k = 0; k < 16; ++k) {
        grz[k] = pkh(whh[grow * 32 + 2 * k],     whh[grow * 32 + 2 * k + 1]);
        wn2[k] = pkh(whh[(64 + m) * 32 + 2 * k], whh[(64 + m) * 32 + 2 * k + 1]);
    }
    const float brz = bhh[grow];
    const float bhn = bhh[64 + m];

    const fv4* A4 = (const fv4*)A;     // [chain*8 + slot]
    const fv4* B4 = (const fv4*)B;     // [t*8 + slot]
    const fv4 alo = A4[c * 8 + q];
    const fv4 ahi = A4[c * 8 + 4 + q];

    // chunk staging: this lane supplies timestep c0 + m0
    fv4 blo = B4[m0 * 8 + q], bhi = B4[m0 * 8 + 4 + q];   // chunk 0

    float h_l = 0.f;                   // h_m (mirrored in both halves)

    for (int c0 = 0; c0 < 1024; c0 += 16) {
        // ---- X-chunk: 6 MFMAs over 16 timesteps -> LDS ----
        uv4 xb;
#pragma unroll
        for (int r = 0; r < 4; ++r)
            xb[r] = pkh(fmaxf(alo[r] + blo[r], 0.f), fmaxf(ahi[r] + bhi[r], 0.f));
        hv8 xf = __builtin_bit_cast(hv8, xb);

        int nc = (c0 + 16) & 1023;     // prefetch next chunk's B rows
        blo = B4[(nc + m0) * 8 + q];
        bhi = B4[(nc + m0) * 8 + 4 + q];

#pragma unroll
        for (int T = 0; T < 6; ++T) {
            fv4 D = __builtin_amdgcn_mfma_f32_16x16x32_f16(xf, WI[T], splat4(bi[T]), 0, 0, 0);
            if (T < 4) {               // r/z tiles: store exp(-XG) (off-path)
#pragma unroll
                for (int r = 0; r < 4; ++r) xg[T][4 * q + r][m0] = __expf(-D[r]);
            } else {                   // n tiles: raw XG
#pragma unroll
                for (int r = 0; r < 4; ++r) xg[T][4 * q + r][m0] = D[r];
            }
        }
        __syncthreads();

        // preload X pre-acts for step 0
        const int Tq = m >> 4;         // 0 for m<16, 1 for m>=16
        const int mc = m & 15;
        float er = xg[Tq][0][mc];      // exp(-xr)
        float ez = xg[2 + Tq][0][mc];  // exp(-xz)
        float xn = xg[4 + Tq][0][mc];  // raw xn

#pragma unroll
        for (int it = 0; it < 16; ++it) {
            // ---- broadcast h: pack f16 pairs in even lanes, 16x readlane ----
            float hnb = dpp_xor1(h_l);             // lane 2k gets h[2k+1]
            hv2 hp;
            hp.x = (_Float16)h_l;                  // RNE, matches old ds path
            hp.y = (_Float16)hnb;
            unsigned pk = __builtin_bit_cast(unsigned, hp);
            unsigned Hs[16];
#pragma unroll
            for (int k = 0; k < 16; ++k)
                Hs[k] = (unsigned)__builtin_amdgcn_readlane((int)pk, 2 * k);

            // ---- r/z half-split: 16 dot2, four 4-deep chains ----
            float ga = brz, gb = 0.f, gc = 0.f, gd = 0.f;
#pragma unroll
            for (int k = 0; k < 4; ++k) {
                ga = d2(grz[k],      Hs[k],      ga);
                gb = d2(grz[k + 4],  Hs[k + 4],  gb);
                gc = d2(grz[k + 8],  Hs[k + 8],  gc);
                gd = d2(grz[k + 12], Hs[k + 12], gd);
            }
            float gfull = (ga + gb) + (gc + gd);
            float hr, hz;
            half_swap(gfull, hr, hz);              // hr from lanes<32, hz from >=32

            // start the r/z exponentials early (overlap with n dot2 issue)
            float ehr = __expf(-hr);
            float ehz = __expf(-hz);

            // ---- n gate: full 32-k dot, mirrored in both halves ----
            float na = bhn, nb2 = 0.f, nc2 = 0.f, nd2 = 0.f;
#pragma unroll
            for (int k = 0; k < 4; ++k) {
                na  = d2(wn2[k],      Hs[k],      na);
                nb2 = d2(wn2[k + 4],  Hs[k + 4],  nb2);
                nc2 = d2(wn2[k + 8],  Hs[k + 8],  nc2);
                nd2 = d2(wn2[k + 12], Hs[k + 12], nd2);
            }
            float hn = (na + nb2) + (nc2 + nd2);

            // ---- branch-free prefetch of next step's X ----
            int nt = (it + 1) & 15;
            float ner = xg[Tq][nt][mc];
            float nez = xg[2 + Tq][nt][mc];
            float nxn = xg[4 + Tq][nt][mc];

            // ---- gates + update, exp-factored sigmoids (bit-identical) ----
            float r = frcp(fmaf(er, ehr, 1.f));
            float z = frcp(fmaf(ez, ehz, 1.f));
            float n = 1.f - 2.f * frcp(__expf(2.f * (xn + r * hn)) + 1.f);
            h_l = (1.f - z) * n + z * h_l;

            er = ner; ez = nez; xn = nxn;
        }
        __syncthreads();
    }

    if (l < 32) h_out[c * 32 + m] = h_l;
}

// ---------------------------------------------------------------------------
// K5: classifier. out[i,o] = sum_k clf_w[o,k]*h2[i,k] + clf_b[o]  (fp32 out)
// ---------------------------------------------------------------------------
__global__ void clf_kernel(const float* __restrict__ h2v, const float* __restrict__ w,
                           const float* __restrict__ bias, float* __restrict__ out) {
    int idx = blockIdx.x * 256 + threadIdx.x;      // 0..3071
    if (idx >= 3072) return;
    int i = idx / 3, o = idx - i * 3;
    float s = bias[o];
#pragma unroll
    for (int k = 0; k < 32; ++k) s += w[o * 32 + k] * h2v[i * 32 + k];
    out[idx] = s;
}

extern "C" void kernel_launch(void* const* d_in, const int* in_sizes, int n_in,
                              void* d_out, int out_size, void* d_ws, size_t ws_size,
                              hipStream_t stream) {
    const float* x       = (const float*)d_in[0];
    const float* p1w     = (const float*)d_in[1];
    const float* p1b     = (const float*)d_in[2];
    const float* g1_wih  = (const float*)d_in[3];
    const float* g1_whh  = (const float*)d_in[4];
    const float* g1_bih  = (const float*)d_in[5];
    const float* g1_bhh  = (const float*)d_in[6];
    const float* p2w     = (const float*)d_in[7];
    const float* p2b     = (const float*)d_in[8];
    const float* g2_wih  = (const float*)d_in[9];
    const float* g2_whh  = (const float*)d_in[10];
    const float* g2_bih  = (const float*)d_in[11];
    const float* g2_bhh  = (const float*)d_in[12];
    const float* clfw    = (const float*)d_in[13];
    const float* clfb    = (const float*)d_in[14];

    // Workspace layout (reused across stages; 3 x 32768 floats = 384 KB):
    float* ws = (float*)d_ws;
    float* A  = ws;              // A1 then A2
    float* Bt = ws + 32768;      // B1 then B2
    float* h  = ws + 65536;      // h1 then h2

    proj1_kernel<<<128, 256, 0, stream>>>(x, p1w, p1b, A, Bt);
    gru_kernel<<<1024, 64, 0, stream>>>(A, Bt, g1_wih, g1_whh, g1_bih, g1_bhh, h);
    proj2_kernel<<<128, 256, 0, stream>>>(h, p2w, p2b, A, Bt);
    gru_kernel<<<1024, 64, 0, stream>>>(A, Bt, g2_wih, g2_whh, g2_bih, g2_bhh, h);
    clf_kernel<<<12, 256, 0, stream>>>(h, clfw, clfb, (float*)d_out);
}

// Round 2
// 456.055 us; speedup vs baseline: 1.2529x; 1.0898x over previous
//
#include <hip/hip_runtime.h>

// N=1024, D=16, H=32, 3H=96.  All tensors fp32 (per reference dtypes).

typedef _Float16 hv2 __attribute__((ext_vector_type(2)));
typedef _Float16 hv8 __attribute__((ext_vector_type(8)));
typedef float    fv4 __attribute__((ext_vector_type(4)));
typedef unsigned uv4 __attribute__((ext_vector_type(4)));

// pack two fp32 -> f16 pair bits (v_cvt_pkrtz_f16_f32) -- weights only (RTZ)
__device__ __forceinline__ unsigned pkh(float a, float b) {
    auto t = __builtin_amdgcn_cvt_pkrtz(a, b);
    return __builtin_bit_cast(unsigned, t);
}
__device__ __forceinline__ fv4 splat4(float v) { return fv4{v, v, v, v}; }
// fast reciprocal: v_rcp_f32 (~1 ulp; verified accuracy-neutral)
#if __has_builtin(__builtin_amdgcn_rcpf)
__device__ __forceinline__ float frcp(float x) { return __builtin_amdgcn_rcpf(x); }
#else
__device__ __forceinline__ float frcp(float x) { return 1.f / x; }
#endif
// bare v_exp_f32: computes 2^x.  All weight/bias prescaling makes every
// exponential a single exp2 (no v_mul by log2e on the serial path).
#if __has_builtin(__builtin_amdgcn_exp2f)
__device__ __forceinline__ float fexp2(float x) { return __builtin_amdgcn_exp2f(x); }
#else
__device__ __forceinline__ float fexp2(float x) { return exp2f(x); }
#endif
// dot2: c += a.x*b.x + a.y*b.y   (f16 inputs, f32 accumulate)
#if __has_builtin(__builtin_amdgcn_fdot2)
__device__ __forceinline__ float d2(unsigned a, unsigned b, float c) {
    return __builtin_amdgcn_fdot2(__builtin_bit_cast(hv2, a),
                                  __builtin_bit_cast(hv2, b), c, false);
}
#else
__device__ __forceinline__ float d2(unsigned a, unsigned b, float c) {
    hv2 x = __builtin_bit_cast(hv2, a), y = __builtin_bit_cast(hv2, b);
    return fmaf((float)x.x, (float)y.x, fmaf((float)x.y, (float)y.y, c));
}
#endif
// lane 2k reads lane 2k+1 (quad_perm [1,0,3,2] = 0xB1); all lanes active
__device__ __forceinline__ float dpp_xor1(float x) {
    int r = __builtin_amdgcn_update_dpp(0, __builtin_bit_cast(int, x),
                                        0xB1, 0xF, 0xF, true);
    return __builtin_bit_cast(float, r);
}
// v_permlane32_swap_b32 d, s  (d=s=x):
//   d := x's lanes 0..31 replicated to both halves
//   s := x's lanes 32..63 replicated to both halves
__device__ __forceinline__ void half_swap(float x, float& lo_all, float& hi_all) {
    float d = x, s = x;
    asm("v_permlane32_swap_b32 %0, %1" : "+v"(d), "+v"(s));
    lo_all = d;
    hi_all = s;
}

// log2(e) scale constants (folded into weights/biases at setup)
#define SRZ (-1.44269504088896341f)   /* r/z: exp(-g) = exp2(SRZ*g) */
#define SN  ( 2.88539008177792682f)   /* n:   exp(2y) = exp2(SN*y)  */

// ---------------------------------------------------------------------------
// K1/K3: pairwise rank-split (unchanged, proven).
// ---------------------------------------------------------------------------
__global__ void proj1_kernel(const float* __restrict__ x, const float* __restrict__ w,
                             const float* __restrict__ bias,
                             float* __restrict__ A, float* __restrict__ B) {
    int idx = blockIdx.x * 256 + threadIdx.x;      // 0..32767
    int i = idx >> 5, h = idx & 31;
    float sa = bias[h];
    float sb = 0.f;
#pragma unroll
    for (int d = 0; d < 16; ++d) {
        float xv = x[i * 16 + d];
        float wa = w[h * 32 + d];
        float wb = w[h * 32 + 16 + d];
        sa += (wa - wb) * xv;
        sb += wb * xv;
    }
    A[i * 32 + h] = sa;
    B[i * 32 + h] = sb;
}

__global__ void proj2_kernel(const float* __restrict__ h1, const float* __restrict__ w,
                             const float* __restrict__ bias,
                             float* __restrict__ A, float* __restrict__ B) {
    int idx = blockIdx.x * 256 + threadIdx.x;      // 0..32767
    int i = idx >> 5, h = idx & 31;
    float sa = bias[h];
    float sb = 0.f;
#pragma unroll
    for (int k = 0; k < 32; ++k) {
        float hv = h1[i * 32 + k];
        float wa = w[h * 64 + k];
        float wb = w[h * 64 + 32 + k];
        sa += (wa - wb) * hv;
        sb += wb * hv;
    }
    A[i * 32 + h] = sa;
    B[i * 32 + h] = sb;
}

// ---------------------------------------------------------------------------
// GRU, one chain per wave, 1024 blocks (1 wave on every SIMD).
//   CHUNK phase (per 16 steps, off the serial path): XG via 6 MFMAs.  Wih and
//   bih are prescaled (r/z tiles by SRZ, n tiles by SN) so r/z tiles store
//   exp2(D) = exp(-xg) with a bare v_exp, n tiles store SN*xn raw.  Layout is
//   now [tile][col][t] (t contiguous, pad 20) -> per-MFMA ds_write_b128 and
//   per-4-step ds_read_b128 on the serial side.
//   SERIAL phase (per step):
//     * h broadcast: DPP pair-pack -> 16x v_readlane (wave-uniform dot2 scalar)
//     * r/z half-split (lanes<32 r-rows, >=32 z-rows) + 1 permlane32_swap
//     * whh rows prescaled by SRZ/SN -> all exponentials are bare v_exp
//     * tail refactor: h' = fma(-2(1-z), rcp(E+1), zh+(1-z)); the z-branch
//       terms compute while the r->n exp chain is in flight.
//   EPILOGUE: layer 2 fuses the classifier (bit-identical fp32 math) and
//   writes d_out directly.
// ---------------------------------------------------------------------------
__global__ __launch_bounds__(64, 1) void gru_kernel(
    const float* __restrict__ A, const float* __restrict__ B,
    const float* __restrict__ wih, const float* __restrict__ whh,
    const float* __restrict__ bih, const float* __restrict__ bhh,
    float* __restrict__ h_out,
    const float* __restrict__ clfw, const float* __restrict__ clfb,
    float* __restrict__ out3) {
    const int l = threadIdx.x;         // 0..63
    const int q = l >> 4;              // k-slot group (chunk MFMA)
    const int m0 = l & 15;             // MFMA col
    const int m = l & 31;              // gate/hidden index (halves mirrored)
    const int c = blockIdx.x;          // chain

    __shared__ float xg[6][16][20];    // [tile][col][t_local] (+pad 4)

    // ---- chunk-phase weights: Wih B-frags, prescaled per-tile ----
    hv8 WI[6];
#pragma unroll
    for (int T = 0; T < 6; ++T) {
        const float sc = (T < 4) ? SRZ : SN;
        int g = 16 * T + m0;
        uv4 wi;
#pragma unroll
        for (int r = 0; r < 4; ++r) {
            int lo = 4 * q + r;
            wi[r] = pkh(wih[g * 32 + lo] * sc, wih[g * 32 + lo + 16] * sc);
        }
        WI[T] = __builtin_bit_cast(hv8, wi);
    }
    float bi[6];
#pragma unroll
    for (int T = 0; T < 6; ++T) bi[T] = bih[16 * T + m0] * ((T < 4) ? SRZ : SN);

    // ---- serial-phase weights, prescaled ----
    // lanes<32: whh r-rows (m);  lanes>=32: whh z-rows (32+m).  n-rows mirrored.
    const int grow = (l < 32) ? m : (32 + m);
    unsigned grz[16], wn2[16];
#pragma unroll
    for (int k = 0; k < 16; ++k) {
        grz[k] = pkh(whh[grow * 32 + 2 * k] * SRZ,     whh[grow * 32 + 2 * k + 1] * SRZ);
        wn2[k] = pkh(whh[(64 + m) * 32 + 2 * k] * SN,  whh[(64 + m) * 32 + 2 * k + 1] * SN);
    }
    const float brz  = bhh[grow] * SRZ;
    const float bhn2 = bhh[64 + m] * SN;

    const fv4* A4 = (const fv4*)A;     // [chain*8 + slot]
    const fv4* B4 = (const fv4*)B;     // [t*8 + slot]
    const fv4 alo = A4[c * 8 + q];
    const fv4 ahi = A4[c * 8 + 4 + q];

    // chunk staging: this lane supplies timestep c0 + m0
    fv4 blo = B4[m0 * 8 + q], bhi = B4[m0 * 8 + 4 + q];   // chunk 0

    float h_l = 0.f;                   // h_m (mirrored in both halves)

    const int Tq = m >> 4;             // 0 for m<16, 1 for m>=16
    const int mc = m & 15;

    for (int c0 = 0; c0 < 1024; c0 += 16) {
        // ---- X-chunk: 6 MFMAs over 16 timesteps -> LDS (b128 stores) ----
        uv4 xb;
#pragma unroll
        for (int r = 0; r < 4; ++r)
            xb[r] = pkh(fmaxf(alo[r] + blo[r], 0.f), fmaxf(ahi[r] + bhi[r], 0.f));
        hv8 xf = __builtin_bit_cast(hv8, xb);

        int nc = (c0 + 16) & 1023;     // prefetch next chunk's B rows
        blo = B4[(nc + m0) * 8 + q];
        bhi = B4[(nc + m0) * 8 + 4 + q];

#pragma unroll
        for (int T = 0; T < 6; ++T) {
            fv4 D = __builtin_amdgcn_mfma_f32_16x16x32_f16(xf, WI[T], splat4(bi[T]), 0, 0, 0);
            fv4 e;
            if (T < 4) {               // r/z tiles: exp2 of prescaled preact
#pragma unroll
                for (int r = 0; r < 4; ++r) e[r] = fexp2(D[r]);
            } else {                   // n tiles: prescaled raw preact
                e = D;
            }
            // D[r] is timestep 4q+r, col m0: contiguous t -> one b128 store
            *(fv4*)&xg[T][m0][4 * q] = e;
        }
        __syncthreads();

        // preload X quads for group 0 (4 steps per quad)
        fv4 Er = *(const fv4*)&xg[Tq][mc][0];
        fv4 Ez = *(const fv4*)&xg[2 + Tq][mc][0];
        fv4 Xn = *(const fv4*)&xg[4 + Tq][mc][0];

#pragma unroll
        for (int g = 0; g < 4; ++g) {
            const fv4 cEr = Er, cEz = Ez, cXn = Xn;
            int ng = (g + 1) & 3;      // branch-free next-group prefetch
            Er = *(const fv4*)&xg[Tq][mc][4 * ng];
            Ez = *(const fv4*)&xg[2 + Tq][mc][4 * ng];
            Xn = *(const fv4*)&xg[4 + Tq][mc][4 * ng];

#pragma unroll
            for (int j = 0; j < 4; ++j) {
                const float er = cEr[j];   // exp(-xr)
                const float ez = cEz[j];   // exp(-xz)
                const float xn = cXn[j];   // SN*xn

                // ---- broadcast h: pack f16 pairs in even lanes, 16x readlane ----
                float hnb = dpp_xor1(h_l);             // lane 2k gets h[2k+1]
                hv2 hp;
                hp.x = (_Float16)h_l;                  // RNE
                hp.y = (_Float16)hnb;
                unsigned pk = __builtin_bit_cast(unsigned, hp);
                unsigned Hs[16];
#pragma unroll
                for (int k = 0; k < 16; ++k)
                    Hs[k] = (unsigned)__builtin_amdgcn_readlane((int)pk, 2 * k);

                // ---- r/z half-split: 16 dot2, four 4-deep chains ----
                float ga = brz, gb = 0.f, gc = 0.f, gd = 0.f;
#pragma unroll
                for (int k = 0; k < 4; ++k) {
                    ga = d2(grz[k],      Hs[k],      ga);
                    gb = d2(grz[k + 4],  Hs[k + 4],  gb);
                    gc = d2(grz[k + 8],  Hs[k + 8],  gc);
                    gd = d2(grz[k + 12], Hs[k + 12], gd);
                }
                float gfull = (ga + gb) + (gc + gd);   // SRZ*(bh + whh.h)
                float hrs, hzs;
                half_swap(gfull, hrs, hzs);

                // bare v_exp (prescaled) -- starts while n dots issue
                float ehr = fexp2(hrs);                // exp(-hr)
                float ehz = fexp2(hzs);                // exp(-hz)

                // ---- n gate: full 32-k dot, mirrored, prescaled by SN ----
                float na = bhn2, nb2 = 0.f, nc2 = 0.f, nd2 = 0.f;
#pragma unroll
                for (int k = 0; k < 4; ++k) {
                    na  = d2(wn2[k],      Hs[k],      na);
                    nb2 = d2(wn2[k + 4],  Hs[k + 4],  nb2);
                    nc2 = d2(wn2[k + 8],  Hs[k + 8],  nc2);
                    nd2 = d2(wn2[k + 12], Hs[k + 12], nd2);
                }
                float hn2 = (na + nb2) + (nc2 + nd2);  // SN*(bh + whh.h)

                // ---- gates.  z-branch terms first (ready early), then the
                //      serial r->E chain, ending in a single rcp+fma. ----
                float z   = frcp(fmaf(ez, ehz, 1.f));  // sigmoid(xz+hz)
                float zh  = z * h_l;
                float omz = 1.f - z;
                float s   = zh + omz;
                float t2  = -2.f * omz;

                float r  = frcp(fmaf(er, ehr, 1.f));   // sigmoid(xr+hr)
                float y  = fmaf(r, hn2, xn);           // SN*(xn_raw + r*hn_raw)
                float E  = fexp2(y);                   // exp(2*tanh_arg)
                float rE = frcp(E + 1.f);
                h_l = fmaf(t2, rE, s);                 // (1-z)*tanh + z*h
            }
        }
        __syncthreads();
    }

    if (clfw) {
        // ---- fused classifier (layer 2): bit-identical to old clf_kernel ----
        float* hs = (float*)xg;
        if (l < 32) hs[m] = h_l;
        __syncthreads();
        if (l < 3) {
            float s = clfb[l];
#pragma unroll
            for (int k = 0; k < 32; ++k) s += clfw[l * 32 + k] * hs[k];
            out3[c * 3 + l] = s;
        }
    } else {
        if (l < 32) h_out[c * 32 + m] = h_l;
    }
}

extern "C" void kernel_launch(void* const* d_in, const int* in_sizes, int n_in,
                              void* d_out, int out_size, void* d_ws, size_t ws_size,
                              hipStream_t stream) {
    const float* x       = (const float*)d_in[0];
    const float* p1w     = (const float*)d_in[1];
    const float* p1b     = (const float*)d_in[2];
    const float* g1_wih  = (const float*)d_in[3];
    const float* g1_whh  = (const float*)d_in[4];
    const float* g1_bih  = (const float*)d_in[5];
    const float* g1_bhh  = (const float*)d_in[6];
    const float* p2w     = (const float*)d_in[7];
    const float* p2b     = (const float*)d_in[8];
    const float* g2_wih  = (const float*)d_in[9];
    const float* g2_whh  = (const float*)d_in[10];
    const float* g2_bih  = (const float*)d_in[11];
    const float* g2_bhh  = (const float*)d_in[12];
    const float* clfw    = (const float*)d_in[13];
    const float* clfb    = (const float*)d_in[14];

    // Workspace layout (reused across stages; 3 x 32768 floats = 384 KB):
    float* ws = (float*)d_ws;
    float* A  = ws;              // A1 then A2
    float* Bt = ws + 32768;      // B1 then B2
    float* h  = ws + 65536;      // h1

    proj1_kernel<<<128, 256, 0, stream>>>(x, p1w, p1b, A, Bt);
    gru_kernel<<<1024, 64, 0, stream>>>(A, Bt, g1_wih, g1_whh, g1_bih, g1_bhh, h,
                                        nullptr, nullptr, nullptr);
    proj2_kernel<<<128, 256, 0, stream>>>(h, p2w, p2b, A, Bt);
    gru_kernel<<<1024, 64, 0, stream>>>(A, Bt, g2_wih, g2_whh, g2_bih, g2_bhh, h,
                                        clfw, clfb, (float*)d_out);
}

// Round 4
// 439.209 us; speedup vs baseline: 1.3010x; 1.0384x over previous
//
#include <hip/hip_runtime.h>

// N=1024, D=16, H=32, 3H=96.  All tensors fp32 (per reference dtypes).

typedef _Float16 hv2 __attribute__((ext_vector_type(2)));
typedef _Float16 hv8 __attribute__((ext_vector_type(8)));
typedef float    fv4 __attribute__((ext_vector_type(4)));
typedef unsigned uv4 __attribute__((ext_vector_type(4)));

// pack two fp32 -> f16 pair bits (v_cvt_pkrtz_f16_f32) -- weights only (RTZ)
__device__ __forceinline__ unsigned pkh(float a, float b) {
    auto t = __builtin_amdgcn_cvt_pkrtz(a, b);
    return __builtin_bit_cast(unsigned, t);
}
__device__ __forceinline__ fv4 splat4(float v) { return fv4{v, v, v, v}; }
// fast reciprocal: v_rcp_f32 (~1 ulp; verified accuracy-neutral)
#if __has_builtin(__builtin_amdgcn_rcpf)
__device__ __forceinline__ float frcp(float x) { return __builtin_amdgcn_rcpf(x); }
#else
__device__ __forceinline__ float frcp(float x) { return 1.f / x; }
#endif
// bare v_exp_f32 (2^x); all weights/biases prescaled by log2e factors
#if __has_builtin(__builtin_amdgcn_exp2f)
__device__ __forceinline__ float fexp2(float x) { return __builtin_amdgcn_exp2f(x); }
#else
__device__ __forceinline__ float fexp2(float x) { return exp2f(x); }
#endif
// dot2: c += a.x*b.x + a.y*b.y   (f16 inputs, f32 accumulate)
#if __has_builtin(__builtin_amdgcn_fdot2)
__device__ __forceinline__ float d2(unsigned a, unsigned b, float c) {
    return __builtin_amdgcn_fdot2(__builtin_bit_cast(hv2, a),
                                  __builtin_bit_cast(hv2, b), c, false);
}
#else
__device__ __forceinline__ float d2(unsigned a, unsigned b, float c) {
    hv2 x = __builtin_bit_cast(hv2, a), y = __builtin_bit_cast(hv2, b);
    return fmaf((float)x.x, (float)y.x, fmaf((float)x.y, (float)y.y, c));
}
#endif
// lane 2k reads lane 2k+1 (quad_perm [1,0,3,2] = 0xB1); all lanes active
__device__ __forceinline__ float dpp_xor1(float x) {
    int r = __builtin_amdgcn_update_dpp(0, __builtin_bit_cast(int, x),
                                        0xB1, 0xF, 0xF, true);
    return __builtin_bit_cast(float, r);
}
// v_permlane32_swap_b32 d, s  (d=s=x):
//   lo_all := x's lanes 0..31 replicated to both halves   (R1/R2-proven orientation)
//   hi_all := x's lanes 32..63 replicated to both halves
__device__ __forceinline__ void half_swap(float x, float& lo_all, float& hi_all) {
    float d = x, s = x;
    asm("v_permlane32_swap_b32 %0, %1" : "+v"(d), "+v"(s));
    lo_all = d;
    hi_all = s;
}

// log2(e) scale constants (folded into weights/biases at setup)
#define SRZ (-1.44269504088896341f)   /* r/z: exp(-g) = exp2(SRZ*g) */
#define SN  ( 2.88539008177792682f)   /* n:   exp(2y) = exp2(SN*y)  */

// ---------------------------------------------------------------------------
// K1/K3: pairwise rank-split (unchanged, proven).
// ---------------------------------------------------------------------------
__global__ void proj1_kernel(const float* __restrict__ x, const float* __restrict__ w,
                             const float* __restrict__ bias,
                             float* __restrict__ A, float* __restrict__ B) {
    int idx = blockIdx.x * 256 + threadIdx.x;      // 0..32767
    int i = idx >> 5, h = idx & 31;
    float sa = bias[h];
    float sb = 0.f;
#pragma unroll
    for (int d = 0; d < 16; ++d) {
        float xv = x[i * 16 + d];
        float wa = w[h * 32 + d];
        float wb = w[h * 32 + 16 + d];
        sa += (wa - wb) * xv;
        sb += wb * xv;
    }
    A[i * 32 + h] = sa;
    B[i * 32 + h] = sb;
}

__global__ void proj2_kernel(const float* __restrict__ h1, const float* __restrict__ w,
                             const float* __restrict__ bias,
                             float* __restrict__ A, float* __restrict__ B) {
    int idx = blockIdx.x * 256 + threadIdx.x;      // 0..32767
    int i = idx >> 5, h = idx & 31;
    float sa = bias[h];
    float sb = 0.f;
#pragma unroll
    for (int k = 0; k < 32; ++k) {
        float hv = h1[i * 32 + k];
        float wa = w[h * 64 + k];
        float wb = w[h * 64 + 32 + k];
        sa += (wa - wb) * hv;
        sb += wb * hv;
    }
    A[i * 32 + h] = sa;
    B[i * 32 + h] = sb;
}

// ---------------------------------------------------------------------------
// GRU, one chain per wave, 1024 blocks (1 wave on every SIMD).
//   R4 = R2's proven sync skeleton (single xg buffer, __syncthreads around
//   chunk/serial -- the R3 barrier-free pipeline NaN'd and is reverted).
//   CHUNK phase (per 16 steps): XG via 6 MFMAs, prescaled Wih/bih; r/z tiles
//   store exp2(D)=exp(-xg), n tiles store SN*xn.  [tile][col][t] layout,
//   b128 stores/loads, 0 bank conflicts (R2-proven).
//   SERIAL phase (per step), changed this round (safe arithmetic only):
//     * own-gate sigmoid: lanes<32 finish the r sigmoid end-to-end (dot,
//       exp2, rcp), lanes>=32 the z sigmoid; ONE permlane32_swap at the END
//       distributes finished sigmoids.  -1 exp2, -1 rcp, -1 fma per step vs
//       R2, and one fewer LDS prefetch stream (own exp(-x) tile only).
//     * tail: h' = fma(-2(1-z), rcp(E+1), fma(z,h,1-z))
//   EPILOGUE: layer 2 fuses the classifier and writes d_out directly.
// ---------------------------------------------------------------------------
__global__ __launch_bounds__(64, 1) void gru_kernel(
    const float* __restrict__ A, const float* __restrict__ B,
    const float* __restrict__ wih, const float* __restrict__ whh,
    const float* __restrict__ bih, const float* __restrict__ bhh,
    float* __restrict__ h_out,
    const float* __restrict__ clfw, const float* __restrict__ clfb,
    float* __restrict__ out3) {
    const int l = threadIdx.x;         // 0..63
    const int q = l >> 4;              // k-slot group (chunk MFMA)
    const int m0 = l & 15;             // MFMA col
    const int m = l & 31;              // gate/hidden index (halves mirrored)
    const int c = blockIdx.x;          // chain

    __shared__ float xg[6][16][20];    // [tile][col][t_local] (+pad 4)

    // ---- chunk-phase weights: Wih B-frags, prescaled per-tile ----
    hv8 WI[6];
#pragma unroll
    for (int T = 0; T < 6; ++T) {
        const float sc = (T < 4) ? SRZ : SN;
        int g = 16 * T + m0;
        uv4 wi;
#pragma unroll
        for (int r = 0; r < 4; ++r) {
            int lo = 4 * q + r;
            wi[r] = pkh(wih[g * 32 + lo] * sc, wih[g * 32 + lo + 16] * sc);
        }
        WI[T] = __builtin_bit_cast(hv8, wi);
    }
    float bi[6];
#pragma unroll
    for (int T = 0; T < 6; ++T) bi[T] = bih[16 * T + m0] * ((T < 4) ? SRZ : SN);

    // ---- serial-phase weights, prescaled ----
    // lanes<32: whh r-rows (m);  lanes>=32: whh z-rows (32+m).  n-rows mirrored.
    const int grow = (l < 32) ? m : (32 + m);
    unsigned grz[16], wn2[16];
#pragma unroll
    for (int k = 0; k < 16; ++k) {
        grz[k] = pkh(whh[grow * 32 + 2 * k] * SRZ,     whh[grow * 32 + 2 * k + 1] * SRZ);
        wn2[k] = pkh(whh[(64 + m) * 32 + 2 * k] * SN,  whh[(64 + m) * 32 + 2 * k + 1] * SN);
    }
    const float brz  = bhh[grow] * SRZ;
    const float bhn2 = bhh[64 + m] * SN;

    const fv4* A4 = (const fv4*)A;     // [chain*8 + slot]
    const fv4* B4 = (const fv4*)B;     // [t*8 + slot]
    const fv4 alo = A4[c * 8 + q];
    const fv4 ahi = A4[c * 8 + 4 + q];

    // chunk staging: this lane supplies timestep c0 + m0
    fv4 blo = B4[m0 * 8 + q], bhi = B4[m0 * 8 + 4 + q];   // chunk 0

    float h_l = 0.f;                   // h_m (mirrored in both halves)

    const int Tq = m >> 4;             // 0 for m<16, 1 for m>=16
    const int mc = m & 15;
    const int TX = (l < 32) ? Tq : (2 + Tq);  // own-gate x-side exp tile

    for (int c0 = 0; c0 < 1024; c0 += 16) {
        // ---- X-chunk: 6 MFMAs over 16 timesteps -> LDS (b128 stores) ----
        uv4 xb;
#pragma unroll
        for (int r = 0; r < 4; ++r)
            xb[r] = pkh(fmaxf(alo[r] + blo[r], 0.f), fmaxf(ahi[r] + bhi[r], 0.f));
        hv8 xf = __builtin_bit_cast(hv8, xb);

        int nc = (c0 + 16) & 1023;     // prefetch next chunk's B rows
        blo = B4[(nc + m0) * 8 + q];
        bhi = B4[(nc + m0) * 8 + 4 + q];

#pragma unroll
        for (int T = 0; T < 6; ++T) {
            fv4 D = __builtin_amdgcn_mfma_f32_16x16x32_f16(xf, WI[T], splat4(bi[T]), 0, 0, 0);
            fv4 e;
            if (T < 4) {               // r/z tiles: exp2 of prescaled preact
#pragma unroll
                for (int r = 0; r < 4; ++r) e[r] = fexp2(D[r]);
            } else {                   // n tiles: prescaled raw preact
                e = D;
            }
            // D[r] is timestep 4q+r, col m0: contiguous t -> one b128 store
            *(fv4*)&xg[T][m0][4 * q] = e;
        }
        __syncthreads();

        // preload X quads for group 0 (4 steps per quad); own-gate tile only
        fv4 Ex = *(const fv4*)&xg[TX][mc][0];
        fv4 Xn = *(const fv4*)&xg[4 + Tq][mc][0];

#pragma unroll
        for (int g = 0; g < 4; ++g) {
            const fv4 cEx = Ex, cXn = Xn;
            int ng = (g + 1) & 3;      // branch-free next-group prefetch
            Ex = *(const fv4*)&xg[TX][mc][4 * ng];
            Xn = *(const fv4*)&xg[4 + Tq][mc][4 * ng];

#pragma unroll
            for (int j = 0; j < 4; ++j) {
                const float ex = cEx[j];   // exp(-x_own)  (r for lo, z for hi)
                const float xn = cXn[j];   // SN*xn

                // ---- broadcast h: pack f16 pairs in even lanes, 16x readlane ----
                float hnb = dpp_xor1(h_l);             // lane 2k gets h[2k+1]
                hv2 hp;
                hp.x = (_Float16)h_l;                  // RNE
                hp.y = (_Float16)hnb;
                unsigned pk = __builtin_bit_cast(unsigned, hp);
                unsigned Hs[16];
#pragma unroll
                for (int k = 0; k < 16; ++k)
                    Hs[k] = (unsigned)__builtin_amdgcn_readlane((int)pk, 2 * k);

                // ---- own-gate dot (r in lo half, z in hi half): 16 dot2 ----
                float ga = brz, gb = 0.f, gc = 0.f, gd = 0.f;
#pragma unroll
                for (int k = 0; k < 4; ++k) {
                    ga = d2(grz[k],      Hs[k],      ga);
                    gb = d2(grz[k + 4],  Hs[k + 4],  gb);
                    gc = d2(grz[k + 8],  Hs[k + 8],  gc);
                    gd = d2(grz[k + 12], Hs[k + 12], gd);
                }
                float gfull = (ga + gb) + (gc + gd);   // SRZ*(bh + whh.h), own gate
                float eh  = fexp2(gfull);              // exp(-h_own)
                float sig = frcp(fmaf(ex, eh, 1.f));   // own-half sigmoid

                // ---- distribute finished sigmoids; z-branch terms early ----
                float r, z;
                half_swap(sig, r, z);                  // r from lo, z from hi
                float omz = 1.f - z;
                float s   = fmaf(z, h_l, omz);         // z*h + (1-z)
                float t2  = -2.f * omz;

                // ---- n gate: full 32-k dot, mirrored, prescaled by SN ----
                float na = bhn2, nb2 = 0.f, nc2 = 0.f, nd2 = 0.f;
#pragma unroll
                for (int k = 0; k < 4; ++k) {
                    na  = d2(wn2[k],      Hs[k],      na);
                    nb2 = d2(wn2[k + 4],  Hs[k + 4],  nb2);
                    nc2 = d2(wn2[k + 8],  Hs[k + 8],  nc2);
                    nd2 = d2(wn2[k + 12], Hs[k + 12], nd2);
                }
                float hn2 = (na + nb2) + (nc2 + nd2);  // SN*(bh + whh.h)

                // ---- n tail ----
                float y  = fmaf(r, hn2, xn);           // SN*(xn_raw + r*hn_raw)
                float E  = fexp2(y);                   // exp(2*tanh_arg)
                float rE = frcp(E + 1.f);
                h_l = fmaf(t2, rE, s);                 // (1-z)*tanh + z*h
            }
        }
        __syncthreads();
    }

    if (clfw) {
        // ---- fused classifier (layer 2): bit-identical fp32 math ----
        float* hs = (float*)xg;
        if (l < 32) hs[m] = h_l;
        __syncthreads();
        if (l < 3) {
            float s = clfb[l];
#pragma unroll
            for (int k = 0; k < 32; ++k) s += clfw[l * 32 + k] * hs[k];
            out3[c * 3 + l] = s;
        }
    } else {
        if (l < 32) h_out[c * 32 + m] = h_l;
    }
}

extern "C" void kernel_launch(void* const* d_in, const int* in_sizes, int n_in,
                              void* d_out, int out_size, void* d_ws, size_t ws_size,
                              hipStream_t stream) {
    const float* x       = (const float*)d_in[0];
    const float* p1w     = (const float*)d_in[1];
    const float* p1b     = (const float*)d_in[2];
    const float* g1_wih  = (const float*)d_in[3];
    const float* g1_whh  = (const float*)d_in[4];
    const float* g1_bih  = (const float*)d_in[5];
    const float* g1_bhh  = (const float*)d_in[6];
    const float* p2w     = (const float*)d_in[7];
    const float* p2b     = (const float*)d_in[8];
    const float* g2_wih  = (const float*)d_in[9];
    const float* g2_whh  = (const float*)d_in[10];
    const float* g2_bih  = (const float*)d_in[11];
    const float* g2_bhh  = (const float*)d_in[12];
    const float* clfw    = (const float*)d_in[13];
    const float* clfb    = (const float*)d_in[14];

    // Workspace layout (reused across stages; 3 x 32768 floats = 384 KB):
    float* ws = (float*)d_ws;
    float* A  = ws;              // A1 then A2
    float* Bt = ws + 32768;      // B1 then B2
    float* h  = ws + 65536;      // h1

    proj1_kernel<<<128, 256, 0, stream>>>(x, p1w, p1b, A, Bt);
    gru_kernel<<<1024, 64, 0, stream>>>(A, Bt, g1_wih, g1_whh, g1_bih, g1_bhh, h,
                                        nullptr, nullptr, nullptr);
    proj2_kernel<<<128, 256, 0, stream>>>(h, p2w, p2b, A, Bt);
    gru_kernel<<<1024, 64, 0, stream>>>(A, Bt, g2_wih, g2_whh, g2_bih, g2_bhh, h,
                                        clfw, clfb, (float*)d_out);
}